// Round 8
// baseline (2119.004 us; speedup 1.0000x reference)
//
#include <hip/hip_runtime.h>

#define NPTS 100000
#define INC 256
#define WID 104
#define WSC 416
#define KOFF 27
#define EPSV 1e-5f
#define NCONVBLK 782

typedef unsigned short u16;
typedef float f32x4 __attribute__((ext_vector_type(4)));
typedef short s16x8 __attribute__((ext_vector_type(8)));

__device__ __forceinline__ u16 f2bf(float f) {
  unsigned u = __builtin_bit_cast(unsigned, f);
  u += 0x7FFFu + ((u >> 16) & 1u);
  return (u16)(u >> 16);
}
__device__ __forceinline__ float bf2f(u16 h) {
  unsigned u = ((unsigned)h) << 16;
  return __builtin_bit_cast(float, u);
}
__device__ __forceinline__ void mfma16(f32x4& d, s16x8 a, s16x8 b) {
  asm("v_mfma_f32_16x16x32_bf16 %0, %1, %2, %0" : "+v"(d) : "v"(a), "v"(b));
}
__device__ __forceinline__ void rawbar() {
  __builtin_amdgcn_s_barrier();
  __builtin_amdgcn_sched_barrier(0);
}

// stats region (floats): ST1 banks 8x832 @0; STC_p banks 8x208 @6656+p*1664; ST3 banks 8x512 @11648
// then 8 ints of barrier counters @15744
#define ST1_OFF 0
#define STC_OFF 6656
#define STC_SZ 1664
#define ST3_OFF 11648
#define BAR_OFF 15744
#define ST_TOTAL 15752

#define SPAD 128   // SPX row stride (elems) = 256B aligned

// ---------------- merged prep: w1/w3 transpose, wc transpose, stats/pad init ----------------
__global__ __launch_bounds__(256) void k_prep(const float* __restrict__ w1,
    const float* __restrict__ w3, const float* __restrict__ wc,
    u16* __restrict__ w1t, u16* __restrict__ w3t, u16* __restrict__ wct,
    float* __restrict__ st, u16* __restrict__ spxp) {
  const int blk = blockIdx.x, t = threadIdx.x;
  if (blk < 832) {
    int i = blk * 256 + t;
    if (i < 416 * 256) {
      int n = i >> 8, k = i & 255;
      w1t[i] = f2bf(w1[(size_t)k * WSC + n]);
    } else {
      int o = i - 416 * 256;
      int n = o / WSC, k = o - n * WSC;
      w3t[o] = f2bf(w3[(size_t)k * INC + n]);
    }
  } else if (blk < 913) {
    __shared__ float w[WID * WID];
    int b = blk - 832;
    const float* s = wc + (size_t)b * WID * WID;
    for (int i = t; i < WID * WID; i += 256) w[i] = s[i];
    __syncthreads();
    u16* d = wct + (size_t)b * 112 * WID;
    for (int o = t; o < 112 * WID; o += 256) {
      int n = o / WID, kin = o - n * WID;
      d[o] = f2bf((n < WID) ? w[kin * WID + n] : 0.f);
    }
  } else {
    const s16x8 hz = {0, 0, 0, 0, 0, 0, 0, 0};
    int b2 = blk - 913;                 // 0..255
    int i = b2 * 256 + t;
    if (i < ST_TOTAL) st[i] = 0.f;
    for (int task = i; task < (NPTS + 1) * 3; task += 256 * 256) {
      int r = task / 3, c = task - 3 * r;
      *(s16x8*)(spxp + (size_t)r * SPAD + (13 + c) * 8) = hz;
    }
    if (b2 == 0 && t < 13)
      *(s16x8*)(spxp + (size_t)NPTS * SPAD + t * 8) = hz;
  }
}

// ---------------- x -> bf16 ----------------
__global__ __launch_bounds__(256) void k_xbf(const float* __restrict__ x,
                                             u16* __restrict__ xb) {
  const int total = NPTS * INC / 8;
  for (int i = blockIdx.x * 256 + threadIdx.x; i < total; i += gridDim.x * 256) {
    const f32x4* s = (const f32x4*)(x + (size_t)i * 8);
    f32x4 v0 = s[0], v1 = s[1];
    s16x8 h;
#pragma unroll
    for (int j = 0; j < 4; ++j) { h[j] = (short)f2bf(v0[j]); h[4 + j] = (short)f2bf(v1[j]); }
    *(s16x8*)(xb + (size_t)i * 8) = h;
  }
}

// ---------------- GEMM1: xb @ W1 -> Y1 slabs [4][N][104] + banked stats ----------------
__global__ __launch_bounds__(256) void k_gemm1(const u16* __restrict__ xb,
    const u16* __restrict__ w1t, u16* __restrict__ ys, float* __restrict__ stats) {
  const int n = blockIdx.x, xcd = n & 7, sgrp = n >> 3;
  const int cb = sgrp & 3, q = sgrp >> 2;
  const int rowbase = (xcd + 8 * q) * 128;
  if (rowbase >= NPTS) return;
  __shared__ char Al[128 * 128];
  __shared__ char Bl[112 * 128];
  const int t = threadIdx.x;
  const int lane = t & 63, wv = t >> 6, lr = lane & 15, lg = lane >> 4;
  const f32x4 fz = {0.f, 0.f, 0.f, 0.f};
  const s16x8 hz = {0, 0, 0, 0, 0, 0, 0, 0};
  f32x4 acc[2][7];
#pragma unroll
  for (int i = 0; i < 2; ++i)
#pragma unroll
    for (int j = 0; j < 7; ++j) acc[i][j] = fz;
  s16x8 pa[4], pb[4];

  auto issue = [&](int st) {
#pragma unroll
    for (int it = 0; it < 4; ++it) {
      int task = t + it * 256, r = task >> 3, c = task & 7, gr = rowbase + r;
      pa[it] = hz;
      if (gr < NPTS) pa[it] = *(const s16x8*)(xb + (size_t)gr * INC + st * 64 + c * 8);
      pb[it] = hz;
      if (task < 832)
        pb[it] = *(const s16x8*)(w1t + (size_t)(cb * WID + r) * INC + st * 64 + c * 8);
    }
  };
  auto writeT = [&]() {
#pragma unroll
    for (int it = 0; it < 4; ++it) {
      int task = t + it * 256, r = task >> 3, c = task & 7;
      *(s16x8*)(Al + ((r * 128 + c * 16) ^ ((r & 7) << 4))) = pa[it];
      if (task < 896) *(s16x8*)(Bl + ((r * 128 + c * 16) ^ ((r & 7) << 4))) = pb[it];
    }
  };
  auto compute = [&]() {
#pragma unroll
    for (int kc = 0; kc < 2; ++kc) {
      int co = kc * 64 + lg * 16;
      s16x8 a[2], b[7];
#pragma unroll
      for (int mt = 0; mt < 2; ++mt) {
        int r = wv * 32 + mt * 16 + lr;
        a[mt] = *(const s16x8*)(Al + ((r * 128 + co) ^ ((r & 7) << 4)));
      }
#pragma unroll
      for (int ct = 0; ct < 7; ++ct) {
        int r = ct * 16 + lr;
        b[ct] = *(const s16x8*)(Bl + ((r * 128 + co) ^ ((r & 7) << 4)));
      }
#pragma unroll
      for (int mt = 0; mt < 2; ++mt)
#pragma unroll
        for (int ct = 0; ct < 7; ++ct) mfma16(acc[mt][ct], a[mt], b[ct]);
    }
  };

  issue(0);
  for (int st = 0; st < 4; ++st) {
    writeT();
    __syncthreads();
    if (st < 3) issue(st + 1);
    compute();
    if (st < 3) rawbar();
  }
  __syncthreads();
  float* S = (float*)Al;
#pragma unroll
  for (int ct = 0; ct < 7; ++ct) {
    float s = 0.f, qq = 0.f;
#pragma unroll
    for (int mt = 0; mt < 2; ++mt)
#pragma unroll
      for (int j = 0; j < 4; ++j) { float v = acc[mt][ct][j]; s += v; qq += v * v; }
    s += __shfl_xor(s, 16); s += __shfl_xor(s, 32);
    qq += __shfl_xor(qq, 16); qq += __shfl_xor(qq, 32);
    if (lane < 16) {
      S[wv * 224 + ct * 16 + lane] = s;
      S[wv * 224 + 112 + ct * 16 + lane] = qq;
    }
  }
  __syncthreads();
  if (t < 224) {
    float v = S[t] + S[224 + t] + S[448 + t] + S[672 + t];
    int cl = (t < 112) ? t : t - 112;
    if (cl < WID) {
      float* base = stats + (sgrp & 7) * 832;
      atomicAdd(base + ((t < 112) ? 0 : WSC) + cb * WID + cl, v);
    }
  }
  __syncthreads();
#pragma unroll
  for (int mt = 0; mt < 2; ++mt)
#pragma unroll
    for (int ct = 0; ct < 7; ++ct)
#pragma unroll
      for (int j = 0; j < 4; ++j) {
        int r = rowbase + wv * 32 + mt * 16 + lg * 4 + j;
        int cl = ct * 16 + lr;
        if (r < NPTS && cl < WID)
          ys[((size_t)cb * NPTS + r) * WID + cl] = f2bf(acc[mt][ct][j]);
      }
}

// ---------------- sparse conv + (optional) fused BN-apply for next branch ----------------
template <int NEXT>
__global__ __launch_bounds__(256, 4) void k_conv(const u16* __restrict__ src,
    const int* __restrict__ nbr, const u16* __restrict__ wct,
    u16* __restrict__ z, float* __restrict__ stats,
    // phase-2 args (NEXT=1):
    const u16* __restrict__ ynext, const float* __restrict__ ST1, int yoff,
    const float* __restrict__ g1, const float* __restrict__ b1,
    const float* __restrict__ gcb, const float* __restrict__ bcb,
    u16* __restrict__ spxout, int* __restrict__ barcnt) {
  __shared__ char Bl[112 * 208 + 64];   // +64 OOB pad for kc3 reads (A=0 there)
  const int t = threadIdx.x, rowbase = blockIdx.x * 128;
  const int lane = t & 63, wv = t >> 6, lr = lane & 15, lg = lane >> 4;
  const f32x4 fz = {0.f, 0.f, 0.f, 0.f};
  f32x4 acc[2][7];
#pragma unroll
  for (int i = 0; i < 2; ++i)
#pragma unroll
    for (int j = 0; j < 7; ++j) acc[i][j] = fz;
  s16x8 pa[2][4], pb[6];

  const int rm0 = rowbase + wv * 32 + lr, rm1 = rm0 + 16;
  const bool ok0 = rm0 < NPTS, ok1 = rm1 < NPTS;
  const int* np0 = nbr + (size_t)(ok0 ? rm0 : 0) * KOFF;
  const int* np1 = nbr + (size_t)(ok1 ? rm1 : 0) * KOFF;
  int in0, in1;

  auto loadB = [&](int k) {
#pragma unroll
    for (int it = 0; it < 6; ++it) {
      int task = t + it * 256;
      if (task < 1456) {
        int r = task / 13, c = task - 13 * r;
        pb[it] = *(const s16x8*)(wct + ((size_t)k * 112 + r) * WID + c * 8);
      }
    }
  };
  auto writeB = [&]() {
#pragma unroll
    for (int it = 0; it < 6; ++it) {
      int task = t + it * 256;
      if (task < 1456) {
        int r = task / 13, c = task - 13 * r;
        *(s16x8*)(Bl + r * 208 + c * 16) = pb[it];
      }
    }
  };

  { // prologue
    int i0 = ok0 ? np0[0] : NPTS, i1 = ok1 ? np1[0] : NPTS;
#pragma unroll
    for (int kc = 0; kc < 4; ++kc) {
      pa[0][kc] = *(const s16x8*)(src + (size_t)i0 * SPAD + kc * 32 + lg * 8);
      pa[1][kc] = *(const s16x8*)(src + (size_t)i1 * SPAD + kc * 32 + lg * 8);
    }
    loadB(0);
    in0 = ok0 ? np0[1] : NPTS;
    in1 = ok1 ? np1[1] : NPTS;
  }

  for (int k = 0; k < KOFF; ++k) {
    writeB();
    __syncthreads();
    if (k < KOFF - 1) loadB(k + 1);
    const bool more = k < KOFF - 1;
#pragma unroll
    for (int kc = 0; kc < 4; ++kc) {
      s16x8 bf[7];
#pragma unroll
      for (int ct = 0; ct < 7; ++ct)
        bf[ct] = *(const s16x8*)(Bl + (ct * 16 + lr) * 208 + kc * 64 + lg * 16);
#pragma unroll
      for (int ct = 0; ct < 7; ++ct) {
        mfma16(acc[0][ct], pa[0][kc], bf[ct]);
        mfma16(acc[1][ct], pa[1][kc], bf[ct]);
      }
      if (more) {
        pa[0][kc] = *(const s16x8*)(src + (size_t)in0 * SPAD + kc * 32 + lg * 8);
        pa[1][kc] = *(const s16x8*)(src + (size_t)in1 * SPAD + kc * 32 + lg * 8);
      }
    }
    if (k < KOFF - 2) {
      in0 = ok0 ? np0[k + 2] : NPTS;
      in1 = ok1 ? np1[k + 2] : NPTS;
    }
    rawbar();
  }

  // stats reduce + banked atomics
  __syncthreads();
  float* S = (float*)Bl;
#pragma unroll
  for (int ct = 0; ct < 7; ++ct) {
    float s = 0.f, qq = 0.f;
#pragma unroll
    for (int mt = 0; mt < 2; ++mt)
#pragma unroll
      for (int j = 0; j < 4; ++j) { float v = acc[mt][ct][j]; s += v; qq += v * v; }
    s += __shfl_xor(s, 16); s += __shfl_xor(s, 32);
    qq += __shfl_xor(qq, 16); qq += __shfl_xor(qq, 32);
    if (lane < 16) {
      S[wv * 224 + ct * 16 + lane] = s;
      S[wv * 224 + 112 + ct * 16 + lane] = qq;
    }
  }
  __syncthreads();
  if (t < 224) {
    float v = S[t] + S[224 + t] + S[448 + t] + S[672 + t];
    int cl = (t < 112) ? t : t - 112;
    if (cl < WID) {
      float* base = stats + (blockIdx.x & 7) * 208;
      atomicAdd(base + ((t < 112) ? 0 : WID) + cl, v);
    }
  }
  // Z write (before barrier; overlaps other blocks' spin)
#pragma unroll
  for (int mt = 0; mt < 2; ++mt)
#pragma unroll
    for (int ct = 0; ct < 7; ++ct)
#pragma unroll
      for (int j = 0; j < 4; ++j) {
        int r = rowbase + wv * 32 + mt * 16 + lg * 4 + j;
        int cl = ct * 16 + lr;
        if (r < NPTS && cl < WID)
          z[(size_t)r * WID + cl] = f2bf(acc[mt][ct][j]);
      }

  if (NEXT) {
    // grid-wide spin barrier (all 782 blocks co-resident: launch_bounds(256,4) -> >=1024 capacity)
    __syncthreads();
    if (t == 0) {
      __threadfence();
      atomicAdd(barcnt, 1);
      while (__hip_atomic_load(barcnt, __ATOMIC_ACQUIRE, __HIP_MEMORY_SCOPE_AGENT) < NCONVBLK) {
        __builtin_amdgcn_s_sleep(8);
      }
    }
    __syncthreads();
    // phase 2: SPX[rows of this block] = relu(bnc(Z)) + relu(bn1(Ynext))
    float* s1c = (float*)Bl;            // 104
    float* f1c = s1c + 104;
    float* szc = f1c + 104;
    float* fzc = szc + 104;
    if (t < 104) {
      float s = 0.f, q = 0.f;
#pragma unroll
      for (int bk = 0; bk < 8; ++bk) { s += ST1[bk * 832 + yoff + t]; q += ST1[bk * 832 + 416 + yoff + t]; }
      float m = s * (1.f / NPTS);
      float var = q * (1.f / NPTS) - m * m;
      float rs = rsqrtf(var + EPSV);
      float sc = rs * g1[yoff + t];
      s1c[t] = sc; f1c[t] = b1[yoff + t] - m * sc;
    } else if (t >= 128 && t < 232) {
      int c = t - 128;
      float s = 0.f, q = 0.f;
#pragma unroll
      for (int bk = 0; bk < 8; ++bk) { s += stats[bk * 208 + c]; q += stats[bk * 208 + 104 + c]; }
      float m = s * (1.f / NPTS);
      float var = q * (1.f / NPTS) - m * m;
      float rs = rsqrtf(var + EPSV);
      float sc = rs * gcb[c];
      szc[c] = sc; fzc[c] = bcb[c] - m * sc;
    }
    __syncthreads();
    for (int task = t; task < 128 * 13; task += 256) {
      int rr = task / 13, cc = task - 13 * rr;
      int r = rowbase + rr;
      if (r >= NPTS) break;
      s16x8 zv = *(const s16x8*)(z + (size_t)r * WID + cc * 8);
      s16x8 yv = *(const s16x8*)(ynext + (size_t)r * WID + cc * 8);
      s16x8 o;
#pragma unroll
      for (int j = 0; j < 8; ++j) {
        int c = cc * 8 + j;
        float f = fmaxf(bf2f((u16)yv[j]) * s1c[c] + f1c[c], 0.f)
                + fmaxf(bf2f((u16)zv[j]) * szc[c] + fzc[c], 0.f);
        o[j] = (short)f2bf(f);
      }
      *(s16x8*)(spxout + (size_t)r * SPAD + cc * 8) = o;
    }
  }
}

// ---------------- GEMM3: BN'd cat @ W3 -> OB bf16 + banked stats ----------------
__global__ __launch_bounds__(256) void k_gemm3(const u16* __restrict__ z0,
    const u16* __restrict__ z1, const u16* __restrict__ z2, const u16* __restrict__ ys,
    const u16* __restrict__ w3t, const float* __restrict__ ST,
    const float* __restrict__ gcp, const float* __restrict__ bcp,
    const float* __restrict__ g1, const float* __restrict__ b1,
    u16* __restrict__ ob, float* __restrict__ st3) {
  const int n = blockIdx.x, xcd = n & 7, sgrp = n >> 3;
  const int cb = sgrp & 1, q = sgrp >> 1;
  const int rowbase = (xcd + 8 * q) * 128;
  if (rowbase >= NPTS) return;
  __shared__ char Al[128 * 128];
  __shared__ char Bl[128 * 128];
  __shared__ float sscl[416], ssft[416];
  const int t = threadIdx.x;
  const int lane = t & 63, wv = t >> 6, lr = lane & 15, lg = lane >> 4;
  const int wr = wv >> 1, wc = wv & 1;
  const f32x4 fz = {0.f, 0.f, 0.f, 0.f};
  const s16x8 hz = {0, 0, 0, 0, 0, 0, 0, 0};
  const u16* ys3 = ys + (size_t)3 * NPTS * WID;
  for (int i = t; i < 416; i += 256) {
    float s = 0.f, qq = 0.f, gg, bb;
    if (i < 312) {
      int p = i / 104, c = i - p * 104;
      const float* base = ST + STC_OFF + p * STC_SZ;
#pragma unroll
      for (int bk = 0; bk < 8; ++bk) { s += base[bk * 208 + c]; qq += base[bk * 208 + 104 + c]; }
      gg = gcp[i]; bb = bcp[i];
    } else {
#pragma unroll
      for (int bk = 0; bk < 8; ++bk) { s += ST[bk * 832 + i]; qq += ST[bk * 832 + 416 + i]; }
      gg = g1[i]; bb = b1[i];
    }
    float m = s * (1.f / NPTS);
    float var = qq * (1.f / NPTS) - m * m;
    float rs = rsqrtf(var + EPSV);
    float sc = rs * gg;
    sscl[i] = sc; ssft[i] = bb - m * sc;
  }
  f32x4 acc[4][4];
#pragma unroll
  for (int i = 0; i < 4; ++i)
#pragma unroll
    for (int j = 0; j < 4; ++j) acc[i][j] = fz;
  s16x8 pa[4], pb[4];

  auto issue = [&](int st) {
#pragma unroll
    for (int it = 0; it < 4; ++it) {
      int task = t + it * 256, r = task >> 3, c = task & 7;
      int gr = rowbase + r, gq = st * 8 + c;
      pa[it] = hz;
      if (gr < NPTS && gq < 52) {
        int p = gq / 13, cc8 = (gq - p * 13) * 8;
        const u16* s = (p == 0) ? z0 + (size_t)gr * WID + cc8
                     : (p == 1) ? z1 + (size_t)gr * WID + cc8
                     : (p == 2) ? z2 + (size_t)gr * WID + cc8
                                : ys3 + (size_t)gr * WID + cc8;
        pa[it] = *(const s16x8*)s;
      }
      int gk = st * 64 + c * 8;
      pb[it] = hz;
      if (gk < WSC) pb[it] = *(const s16x8*)(w3t + (size_t)(cb * 128 + r) * WSC + gk);
    }
  };
  auto writeT = [&](int st) {
#pragma unroll
    for (int it = 0; it < 4; ++it) {
      int task = t + it * 256, r = task >> 3, c = task & 7;
      int gr = rowbase + r, gq = st * 8 + c;
      s16x8 h = hz;
      if (gr < NPTS && gq < 52) {
        int p = gq / 13;
        int colb = p * WID + (gq - p * 13) * 8;
#pragma unroll
        for (int j = 0; j < 8; ++j) {
          float f = fmaxf(bf2f((u16)pa[it][j]) * sscl[colb + j] + ssft[colb + j], 0.f);
          h[j] = (short)f2bf(f);
        }
      }
      *(s16x8*)(Al + ((r * 128 + c * 16) ^ ((r & 7) << 4))) = h;
      *(s16x8*)(Bl + ((r * 128 + c * 16) ^ ((r & 7) << 4))) = pb[it];
    }
  };
  auto compute = [&]() {
#pragma unroll
    for (int kc = 0; kc < 2; ++kc) {
      int co = kc * 64 + lg * 16;
      s16x8 a[4], b[4];
#pragma unroll
      for (int mt = 0; mt < 4; ++mt) {
        int r = wr * 64 + mt * 16 + lr;
        a[mt] = *(const s16x8*)(Al + ((r * 128 + co) ^ ((r & 7) << 4)));
      }
#pragma unroll
      for (int ct = 0; ct < 4; ++ct) {
        int r = wc * 64 + ct * 16 + lr;
        b[ct] = *(const s16x8*)(Bl + ((r * 128 + co) ^ ((r & 7) << 4)));
      }
#pragma unroll
      for (int mt = 0; mt < 4; ++mt)
#pragma unroll
        for (int ct = 0; ct < 4; ++ct) mfma16(acc[mt][ct], a[mt], b[ct]);
    }
  };

  issue(0);
  __syncthreads();
  for (int st = 0; st < 7; ++st) {
    writeT(st);
    __syncthreads();
    if (st < 6) issue(st + 1);
    compute();
    if (st < 6) rawbar();
  }
  __syncthreads();
  float* S = (float*)Al;
#pragma unroll
  for (int ct = 0; ct < 4; ++ct) {
    float s = 0.f, qq = 0.f;
#pragma unroll
    for (int mt = 0; mt < 4; ++mt)
#pragma unroll
      for (int j = 0; j < 4; ++j) { float v = acc[mt][ct][j]; s += v; qq += v * v; }
    s += __shfl_xor(s, 16); s += __shfl_xor(s, 32);
    qq += __shfl_xor(qq, 16); qq += __shfl_xor(qq, 32);
    if (lane < 16) {
      S[wv * 128 + ct * 16 + lane] = s;
      S[wv * 128 + 64 + ct * 16 + lane] = qq;
    }
  }
  __syncthreads();
  {
    float* base = st3 + (sgrp & 7) * 512;
    if (t < 64) atomicAdd(base + cb * 128 + t, S[t] + S[256 + t]);
    else if (t < 128) atomicAdd(base + INC + cb * 128 + (t - 64), S[64 + t - 64] + S[320 + t - 64]);
    else if (t < 192) atomicAdd(base + cb * 128 + 64 + (t - 128), S[128 + t - 128] + S[384 + t - 128]);
    else atomicAdd(base + INC + cb * 128 + 64 + (t - 192), S[192 + t - 192] + S[448 + t - 192]);
  }
#pragma unroll
  for (int mt = 0; mt < 4; ++mt)
#pragma unroll
    for (int ct = 0; ct < 4; ++ct)
#pragma unroll
      for (int j = 0; j < 4; ++j) {
        int r = rowbase + wr * 64 + mt * 16 + lg * 4 + j;
        int col = cb * 128 + wc * 64 + ct * 16 + lr;
        if (r < NPTS) ob[(size_t)r * INC + col] = f2bf(acc[mt][ct][j]);
      }
}

// ---------------- mix0: SPX = relu(bn1(Y slab0)), fused stats ----------------
__global__ __launch_bounds__(256) void k_mix0(const u16* __restrict__ ys,
    const float* __restrict__ ST, const float* __restrict__ g1, const float* __restrict__ b1,
    u16* __restrict__ spx) {
  __shared__ float s1c[104], f1c[104];
  const int t = threadIdx.x;
  if (t < 104) {
    float s = 0.f, q = 0.f;
#pragma unroll
    for (int bk = 0; bk < 8; ++bk) { s += ST[bk * 832 + t]; q += ST[bk * 832 + 416 + t]; }
    float m = s * (1.f / NPTS);
    float var = q * (1.f / NPTS) - m * m;
    float rs = rsqrtf(var + EPSV);
    float sc = rs * g1[t];
    s1c[t] = sc; f1c[t] = b1[t] - m * sc;
  }
  __syncthreads();
  const int total = NPTS * 13;
  for (int i = blockIdx.x * 256 + t; i < total; i += gridDim.x * 256) {
    int r = i / 13, cc = i - r * 13;
    s16x8 y = *(const s16x8*)(ys + (size_t)r * WID + cc * 8);
    s16x8 o;
#pragma unroll
    for (int j = 0; j < 8; ++j) {
      int c = cc * 8 + j;
      o[j] = (short)f2bf(fmaxf(bf2f((u16)y[j]) * s1c[c] + f1c[c], 0.f));
    }
    *(s16x8*)(spx + (size_t)r * SPAD + cc * 8) = o;
  }
}

// ---------------- final: out = relu(bn3(ob) + xb), fused stats ----------------
__global__ __launch_bounds__(256) void k_final(const u16* __restrict__ ob,
    const u16* __restrict__ xb, const float* __restrict__ ST3,
    const float* __restrict__ g3, const float* __restrict__ b3,
    float* __restrict__ out) {
  __shared__ float sc3[256], sf3[256];
  const int t = threadIdx.x;
  {
    float s = 0.f, q = 0.f;
#pragma unroll
    for (int bk = 0; bk < 8; ++bk) { s += ST3[bk * 512 + t]; q += ST3[bk * 512 + 256 + t]; }
    float m = s * (1.f / NPTS);
    float var = q * (1.f / NPTS) - m * m;
    float rs = rsqrtf(var + EPSV);
    float sc = rs * g3[t];
    sc3[t] = sc; sf3[t] = b3[t] - m * sc;
  }
  __syncthreads();
  const int total = NPTS * 32;
  for (int i = blockIdx.x * 256 + t; i < total; i += gridDim.x * 256) {
    int r = i >> 5, cc = i & 31;
    s16x8 o = *(const s16x8*)(ob + (size_t)r * INC + cc * 8);
    s16x8 xv = *(const s16x8*)(xb + (size_t)r * INC + cc * 8);
    f32x4 v0, v1;
#pragma unroll
    for (int j = 0; j < 4; ++j) {
      int c = cc * 8 + j;
      v0[j] = fmaxf(bf2f((u16)o[j]) * sc3[c] + sf3[c] + bf2f((u16)xv[j]), 0.f);
    }
#pragma unroll
    for (int j = 0; j < 4; ++j) {
      int c = cc * 8 + 4 + j;
      v1[j] = fmaxf(bf2f((u16)o[4 + j]) * sc3[c] + sf3[c] + bf2f((u16)xv[4 + j]), 0.f);
    }
    f32x4* dp = (f32x4*)(out + (size_t)r * INC + cc * 8);
    dp[0] = v0; dp[1] = v1;
  }
}

// ---------------- launch ----------------
extern "C" void kernel_launch(void* const* d_in, const int* in_sizes, int n_in,
                              void* d_out, int out_size, void* d_ws, size_t ws_size,
                              hipStream_t stream) {
  const float* x  = (const float*)d_in[0];
  const int* nbr  = (const int*)d_in[1];
  const float* W1 = (const float*)d_in[2];
  const float* g1 = (const float*)d_in[3];
  const float* b1 = (const float*)d_in[4];
  const float* Wc = (const float*)d_in[5];
  const float* gc = (const float*)d_in[6];
  const float* bc = (const float*)d_in[7];
  const float* W3 = (const float*)d_in[8];
  const float* g3 = (const float*)d_in[9];
  const float* b3 = (const float*)d_in[10];
  float* out = (float*)d_out;

  char* ws = (char*)d_ws;
  size_t off = 0;
  auto alloc = [&](size_t nbytes) {
    char* p = ws + off;
    off += (nbytes + 255) & ~(size_t)255;
    return p;
  };
  u16* W1T = (u16*)alloc(416 * 256 * 2);
  u16* W3T = (u16*)alloc(256 * 416 * 2);
  u16* WCT = (u16*)alloc((size_t)3 * 27 * 112 * 104 * 2);
  u16* XB  = (u16*)alloc((size_t)NPTS * INC * 2);
  u16* Y1S = (u16*)alloc((size_t)4 * NPTS * WID * 2);
  u16* Z0  = (u16*)alloc((size_t)NPTS * WID * 2);
  u16* Z1  = (u16*)alloc((size_t)NPTS * WID * 2);
  u16* Z2  = (u16*)alloc((size_t)NPTS * WID * 2);
  u16* OB  = (u16*)alloc((size_t)NPTS * INC * 2);
  u16* SPX = (u16*)alloc((size_t)(NPTS + 1) * SPAD * 2);
  float* ST = (float*)alloc(ST_TOTAL * 4);
  float* ST1  = ST + ST1_OFF;
  float* STC0 = ST + STC_OFF;
  float* STC1 = ST + STC_OFF + STC_SZ;
  float* STC2 = ST + STC_OFF + 2 * STC_SZ;
  float* ST3  = ST + ST3_OFF;
  int* BAR = (int*)(ST + BAR_OFF);

  k_prep<<<1169, 256, 0, stream>>>(W1, W3, Wc, W1T, W3T, WCT, ST, SPX);
  k_xbf<<<2048, 256, 0, stream>>>(x, XB);

  k_gemm1<<<3136, 256, 0, stream>>>(XB, W1T, Y1S, ST1);
  k_mix0<<<2048, 256, 0, stream>>>(Y1S, ST1, g1, b1, SPX);

  const size_t WCL = (size_t)27 * 112 * WID;
  const u16* YS1 = Y1S + (size_t)1 * NPTS * WID;
  const u16* YS2 = Y1S + (size_t)2 * NPTS * WID;
  // branch 0: conv + fused BN-apply producing SPX for branch 1
  k_conv<1><<<NCONVBLK, 256, 0, stream>>>(SPX, nbr, WCT, Z0, STC0,
      YS1, ST1, 104, g1, b1, gc, bc, SPX, BAR);
  // branch 1: conv + fused BN-apply producing SPX for branch 2
  k_conv<1><<<NCONVBLK, 256, 0, stream>>>(SPX, nbr, WCT + WCL, Z1, STC1,
      YS2, ST1, 208, g1, b1, gc + 104, bc + 104, SPX, BAR + 1);
  // branch 2: plain conv
  k_conv<0><<<NCONVBLK, 256, 0, stream>>>(SPX, nbr, WCT + 2 * WCL, Z2, STC2,
      nullptr, nullptr, 0, nullptr, nullptr, nullptr, nullptr, nullptr, nullptr);

  k_gemm3<<<1568, 256, 0, stream>>>(Z0, Z1, Z2, Y1S, W3T, ST, gc, bc, g1, b1, OB, ST3);
  k_final<<<2048, 256, 0, stream>>>(OB, XB, ST3, g3, b3, out);
}

// Round 9
// 700.096 us; speedup vs baseline: 3.0267x; 3.0267x over previous
//
#include <hip/hip_runtime.h>

#define NPTS 100000
#define INC 256
#define WID 104
#define WSC 416
#define KOFF 27
#define EPSV 1e-5f

typedef unsigned short u16;
typedef float f32x4 __attribute__((ext_vector_type(4)));
typedef short s16x8 __attribute__((ext_vector_type(8)));

__device__ __forceinline__ u16 f2bf(float f) {
  unsigned u = __builtin_bit_cast(unsigned, f);
  u += 0x7FFFu + ((u >> 16) & 1u);
  return (u16)(u >> 16);
}
__device__ __forceinline__ float bf2f(u16 h) {
  unsigned u = ((unsigned)h) << 16;
  return __builtin_bit_cast(float, u);
}
__device__ __forceinline__ void mfma16(f32x4& d, s16x8 a, s16x8 b) {
  asm("v_mfma_f32_16x16x32_bf16 %0, %1, %2, %0" : "+v"(d) : "v"(a), "v"(b));
}
__device__ __forceinline__ void rawbar() {
  __builtin_amdgcn_s_barrier();
  __builtin_amdgcn_sched_barrier(0);
}

// stats region (floats): ST1 banks 8x832 @0; STC_p banks 8x208 @6656+p*1664; ST3 banks 8x512 @11648
#define ST1_OFF 0
#define STC_OFF 6656
#define STC_SZ 1664
#define ST3_OFF 11648
#define ST_TOTAL 15744

#define SPAD 128   // SPX row stride (elems) = 256B aligned

// ---------------- merged prep: w1/w3 transpose, wc transpose, stats/pad init, x->bf16 ----------------
__global__ __launch_bounds__(256) void k_prep(const float* __restrict__ w1,
    const float* __restrict__ w3, const float* __restrict__ wc,
    u16* __restrict__ w1t, u16* __restrict__ w3t, u16* __restrict__ wct,
    float* __restrict__ st, u16* __restrict__ spxp,
    const float* __restrict__ x, u16* __restrict__ xb) {
  const int blk = blockIdx.x, t = threadIdx.x;
  if (blk < 832) {
    int i = blk * 256 + t;
    if (i < 416 * 256) {
      int n = i >> 8, k = i & 255;
      w1t[i] = f2bf(w1[(size_t)k * WSC + n]);
    } else {
      int o = i - 416 * 256;
      int n = o / WSC, k = o - n * WSC;
      w3t[o] = f2bf(w3[(size_t)k * INC + n]);
    }
  } else if (blk < 913) {
    __shared__ float w[WID * WID];
    int b = blk - 832;
    const float* s = wc + (size_t)b * WID * WID;
    for (int i = t; i < WID * WID; i += 256) w[i] = s[i];
    __syncthreads();
    u16* d = wct + (size_t)b * 112 * WID;
    for (int o = t; o < 112 * WID; o += 256) {
      int n = o / WID, kin = o - n * WID;
      d[o] = f2bf((n < WID) ? w[kin * WID + n] : 0.f);
    }
  } else if (blk < 1169) {
    const s16x8 hz = {0, 0, 0, 0, 0, 0, 0, 0};
    int b2 = blk - 913;                 // 0..255
    int i = b2 * 256 + t;
    if (i < ST_TOTAL) st[i] = 0.f;
    for (int task = i; task < (NPTS + 1) * 3; task += 256 * 256) {
      int r = task / 3, c = task - 3 * r;
      *(s16x8*)(spxp + (size_t)r * SPAD + (13 + c) * 8) = hz;
    }
    if (b2 == 0 && t < 13)
      *(s16x8*)(spxp + (size_t)NPTS * SPAD + t * 8) = hz;
  } else {
    const int total = NPTS * INC / 8;
    for (int i = (blk - 1169) * 256 + t; i < total; i += 2048 * 256) {
      const f32x4* s = (const f32x4*)(x + (size_t)i * 8);
      f32x4 v0 = s[0], v1 = s[1];
      s16x8 h;
#pragma unroll
      for (int j = 0; j < 4; ++j) { h[j] = (short)f2bf(v0[j]); h[4 + j] = (short)f2bf(v1[j]); }
      *(s16x8*)(xb + (size_t)i * 8) = h;
    }
  }
}

// ---------------- GEMM1: xb @ W1 -> Y1 slabs [4][N][104] + banked stats ----------------
__global__ __launch_bounds__(256) void k_gemm1(const u16* __restrict__ xb,
    const u16* __restrict__ w1t, u16* __restrict__ ys, float* __restrict__ stats) {
  const int n = blockIdx.x, xcd = n & 7, sgrp = n >> 3;
  const int cb = sgrp & 3, q = sgrp >> 2;
  const int rowbase = (xcd + 8 * q) * 128;
  if (rowbase >= NPTS) return;
  __shared__ char Al[128 * 128];
  __shared__ char Bl[112 * 128];
  const int t = threadIdx.x;
  const int lane = t & 63, wv = t >> 6, lr = lane & 15, lg = lane >> 4;
  const f32x4 fz = {0.f, 0.f, 0.f, 0.f};
  const s16x8 hz = {0, 0, 0, 0, 0, 0, 0, 0};
  f32x4 acc[2][7];
#pragma unroll
  for (int i = 0; i < 2; ++i)
#pragma unroll
    for (int j = 0; j < 7; ++j) acc[i][j] = fz;
  s16x8 pa[4], pb[4];

  auto issue = [&](int st) {
#pragma unroll
    for (int it = 0; it < 4; ++it) {
      int task = t + it * 256, r = task >> 3, c = task & 7, gr = rowbase + r;
      pa[it] = hz;
      if (gr < NPTS) pa[it] = *(const s16x8*)(xb + (size_t)gr * INC + st * 64 + c * 8);
      pb[it] = hz;
      if (task < 832)
        pb[it] = *(const s16x8*)(w1t + (size_t)(cb * WID + r) * INC + st * 64 + c * 8);
    }
  };
  auto writeT = [&]() {
#pragma unroll
    for (int it = 0; it < 4; ++it) {
      int task = t + it * 256, r = task >> 3, c = task & 7;
      *(s16x8*)(Al + ((r * 128 + c * 16) ^ ((r & 7) << 4))) = pa[it];
      if (task < 896) *(s16x8*)(Bl + ((r * 128 + c * 16) ^ ((r & 7) << 4))) = pb[it];
    }
  };
  auto compute = [&]() {
#pragma unroll
    for (int kc = 0; kc < 2; ++kc) {
      int co = kc * 64 + lg * 16;
      s16x8 a[2], b[7];
#pragma unroll
      for (int mt = 0; mt < 2; ++mt) {
        int r = wv * 32 + mt * 16 + lr;
        a[mt] = *(const s16x8*)(Al + ((r * 128 + co) ^ ((r & 7) << 4)));
      }
#pragma unroll
      for (int ct = 0; ct < 7; ++ct) {
        int r = ct * 16 + lr;
        b[ct] = *(const s16x8*)(Bl + ((r * 128 + co) ^ ((r & 7) << 4)));
      }
#pragma unroll
      for (int mt = 0; mt < 2; ++mt)
#pragma unroll
        for (int ct = 0; ct < 7; ++ct) mfma16(acc[mt][ct], a[mt], b[ct]);
    }
  };

  issue(0);
  for (int st = 0; st < 4; ++st) {
    writeT();
    __syncthreads();
    if (st < 3) issue(st + 1);
    compute();
    if (st < 3) rawbar();
  }
  __syncthreads();
  float* S = (float*)Al;
#pragma unroll
  for (int ct = 0; ct < 7; ++ct) {
    float s = 0.f, qq = 0.f;
#pragma unroll
    for (int mt = 0; mt < 2; ++mt)
#pragma unroll
      for (int j = 0; j < 4; ++j) { float v = acc[mt][ct][j]; s += v; qq += v * v; }
    s += __shfl_xor(s, 16); s += __shfl_xor(s, 32);
    qq += __shfl_xor(qq, 16); qq += __shfl_xor(qq, 32);
    if (lane < 16) {
      S[wv * 224 + ct * 16 + lane] = s;
      S[wv * 224 + 112 + ct * 16 + lane] = qq;
    }
  }
  __syncthreads();
  if (t < 224) {
    float v = S[t] + S[224 + t] + S[448 + t] + S[672 + t];
    int cl = (t < 112) ? t : t - 112;
    if (cl < WID) {
      float* base = stats + (sgrp & 7) * 832;
      atomicAdd(base + ((t < 112) ? 0 : WSC) + cb * WID + cl, v);
    }
  }
  __syncthreads();
#pragma unroll
  for (int mt = 0; mt < 2; ++mt)
#pragma unroll
    for (int ct = 0; ct < 7; ++ct)
#pragma unroll
      for (int j = 0; j < 4; ++j) {
        int r = rowbase + wv * 32 + mt * 16 + lg * 4 + j;
        int cl = ct * 16 + lr;
        if (r < NPTS && cl < WID)
          ys[((size_t)cb * NPTS + r) * WID + cl] = f2bf(acc[mt][ct][j]);
      }
}

// ---------------- sparse conv: direct-frag rolling gather, B in LDS ----------------
__global__ __launch_bounds__(256) void k_conv(const u16* __restrict__ src,
    const int* __restrict__ nbr, const u16* __restrict__ wct,
    u16* __restrict__ z, float* __restrict__ stats) {
  __shared__ char Bl[112 * 208 + 64];   // +64 OOB pad for kc3 reads (A=0 there)
  const int t = threadIdx.x, rowbase = blockIdx.x * 128;
  const int lane = t & 63, wv = t >> 6, lr = lane & 15, lg = lane >> 4;
  const f32x4 fz = {0.f, 0.f, 0.f, 0.f};
  f32x4 acc[2][7];
#pragma unroll
  for (int i = 0; i < 2; ++i)
#pragma unroll
    for (int j = 0; j < 7; ++j) acc[i][j] = fz;
  s16x8 pa[2][4], pb[6];

  const int rm0 = rowbase + wv * 32 + lr, rm1 = rm0 + 16;
  const bool ok0 = rm0 < NPTS, ok1 = rm1 < NPTS;
  const int* np0 = nbr + (size_t)(ok0 ? rm0 : 0) * KOFF;
  const int* np1 = nbr + (size_t)(ok1 ? rm1 : 0) * KOFF;
  int in0, in1;

  auto loadB = [&](int k) {
#pragma unroll
    for (int it = 0; it < 6; ++it) {
      int task = t + it * 256;
      if (task < 1456) {
        int r = task / 13, c = task - 13 * r;
        pb[it] = *(const s16x8*)(wct + ((size_t)k * 112 + r) * WID + c * 8);
      }
    }
  };
  auto writeB = [&]() {
#pragma unroll
    for (int it = 0; it < 6; ++it) {
      int task = t + it * 256;
      if (task < 1456) {
        int r = task / 13, c = task - 13 * r;
        *(s16x8*)(Bl + r * 208 + c * 16) = pb[it];
      }
    }
  };

  { // prologue
    int i0 = ok0 ? np0[0] : NPTS, i1 = ok1 ? np1[0] : NPTS;
#pragma unroll
    for (int kc = 0; kc < 4; ++kc) {
      pa[0][kc] = *(const s16x8*)(src + (size_t)i0 * SPAD + kc * 32 + lg * 8);
      pa[1][kc] = *(const s16x8*)(src + (size_t)i1 * SPAD + kc * 32 + lg * 8);
    }
    loadB(0);
    in0 = ok0 ? np0[1] : NPTS;
    in1 = ok1 ? np1[1] : NPTS;
  }

  for (int k = 0; k < KOFF; ++k) {
    writeB();
    __syncthreads();
    if (k < KOFF - 1) loadB(k + 1);
    const bool more = k < KOFF - 1;
#pragma unroll
    for (int kc = 0; kc < 4; ++kc) {
      s16x8 bf[7];
#pragma unroll
      for (int ct = 0; ct < 7; ++ct)
        bf[ct] = *(const s16x8*)(Bl + (ct * 16 + lr) * 208 + kc * 64 + lg * 16);
#pragma unroll
      for (int ct = 0; ct < 7; ++ct) {
        mfma16(acc[0][ct], pa[0][kc], bf[ct]);
        mfma16(acc[1][ct], pa[1][kc], bf[ct]);
      }
      if (more) {
        pa[0][kc] = *(const s16x8*)(src + (size_t)in0 * SPAD + kc * 32 + lg * 8);
        pa[1][kc] = *(const s16x8*)(src + (size_t)in1 * SPAD + kc * 32 + lg * 8);
      }
    }
    if (k < KOFF - 2) {
      in0 = ok0 ? np0[k + 2] : NPTS;
      in1 = ok1 ? np1[k + 2] : NPTS;
    }
    rawbar();
  }

  __syncthreads();
  float* S = (float*)Bl;
#pragma unroll
  for (int ct = 0; ct < 7; ++ct) {
    float s = 0.f, qq = 0.f;
#pragma unroll
    for (int mt = 0; mt < 2; ++mt)
#pragma unroll
      for (int j = 0; j < 4; ++j) { float v = acc[mt][ct][j]; s += v; qq += v * v; }
    s += __shfl_xor(s, 16); s += __shfl_xor(s, 32);
    qq += __shfl_xor(qq, 16); qq += __shfl_xor(qq, 32);
    if (lane < 16) {
      S[wv * 224 + ct * 16 + lane] = s;
      S[wv * 224 + 112 + ct * 16 + lane] = qq;
    }
  }
  __syncthreads();
  if (t < 224) {
    float v = S[t] + S[224 + t] + S[448 + t] + S[672 + t];
    int cl = (t < 112) ? t : t - 112;
    if (cl < WID) {
      float* base = stats + (blockIdx.x & 7) * 208;
      atomicAdd(base + ((t < 112) ? 0 : WID) + cl, v);
    }
  }
#pragma unroll
  for (int mt = 0; mt < 2; ++mt)
#pragma unroll
    for (int ct = 0; ct < 7; ++ct)
#pragma unroll
      for (int j = 0; j < 4; ++j) {
        int r = rowbase + wv * 32 + mt * 16 + lg * 4 + j;
        int cl = ct * 16 + lr;
        if (r < NPTS && cl < WID)
          z[(size_t)r * WID + cl] = f2bf(acc[mt][ct][j]);
      }
}

// ---------------- GEMM3: BN'd cat @ W3 -> OB bf16 + banked stats ----------------
__global__ __launch_bounds__(256) void k_gemm3(const u16* __restrict__ z0,
    const u16* __restrict__ z1, const u16* __restrict__ z2, const u16* __restrict__ ys,
    const u16* __restrict__ w3t, const float* __restrict__ ST,
    const float* __restrict__ gcp, const float* __restrict__ bcp,
    const float* __restrict__ g1, const float* __restrict__ b1,
    u16* __restrict__ ob, float* __restrict__ st3) {
  const int n = blockIdx.x, xcd = n & 7, sgrp = n >> 3;
  const int cb = sgrp & 1, q = sgrp >> 1;
  const int rowbase = (xcd + 8 * q) * 128;
  if (rowbase >= NPTS) return;
  __shared__ char Al[128 * 128];
  __shared__ char Bl[128 * 128];
  __shared__ float sscl[416], ssft[416];
  const int t = threadIdx.x;
  const int lane = t & 63, wv = t >> 6, lr = lane & 15, lg = lane >> 4;
  const int wr = wv >> 1, wc = wv & 1;
  const f32x4 fz = {0.f, 0.f, 0.f, 0.f};
  const s16x8 hz = {0, 0, 0, 0, 0, 0, 0, 0};
  const u16* ys3 = ys + (size_t)3 * NPTS * WID;
  for (int i = t; i < 416; i += 256) {
    float s = 0.f, qq = 0.f, gg, bb;
    if (i < 312) {
      int p = i / 104, c = i - p * 104;
      const float* base = ST + STC_OFF + p * STC_SZ;
#pragma unroll
      for (int bk = 0; bk < 8; ++bk) { s += base[bk * 208 + c]; qq += base[bk * 208 + 104 + c]; }
      gg = gcp[i]; bb = bcp[i];
    } else {
#pragma unroll
      for (int bk = 0; bk < 8; ++bk) { s += ST[bk * 832 + i]; qq += ST[bk * 832 + 416 + i]; }
      gg = g1[i]; bb = b1[i];
    }
    float m = s * (1.f / NPTS);
    float var = qq * (1.f / NPTS) - m * m;
    float rs = rsqrtf(var + EPSV);
    float sc = rs * gg;
    sscl[i] = sc; ssft[i] = bb - m * sc;
  }
  f32x4 acc[4][4];
#pragma unroll
  for (int i = 0; i < 4; ++i)
#pragma unroll
    for (int j = 0; j < 4; ++j) acc[i][j] = fz;
  s16x8 pa[4], pb[4];

  auto issue = [&](int st) {
#pragma unroll
    for (int it = 0; it < 4; ++it) {
      int task = t + it * 256, r = task >> 3, c = task & 7;
      int gr = rowbase + r, gq = st * 8 + c;
      pa[it] = hz;
      if (gr < NPTS && gq < 52) {
        int p = gq / 13, cc8 = (gq - p * 13) * 8;
        const u16* s = (p == 0) ? z0 + (size_t)gr * WID + cc8
                     : (p == 1) ? z1 + (size_t)gr * WID + cc8
                     : (p == 2) ? z2 + (size_t)gr * WID + cc8
                                : ys3 + (size_t)gr * WID + cc8;
        pa[it] = *(const s16x8*)s;
      }
      int gk = st * 64 + c * 8;
      pb[it] = hz;
      if (gk < WSC) pb[it] = *(const s16x8*)(w3t + (size_t)(cb * 128 + r) * WSC + gk);
    }
  };
  auto writeT = [&](int st) {
#pragma unroll
    for (int it = 0; it < 4; ++it) {
      int task = t + it * 256, r = task >> 3, c = task & 7;
      int gr = rowbase + r, gq = st * 8 + c;
      s16x8 h = hz;
      if (gr < NPTS && gq < 52) {
        int p = gq / 13;
        int colb = p * WID + (gq - p * 13) * 8;
#pragma unroll
        for (int j = 0; j < 8; ++j) {
          float f = fmaxf(bf2f((u16)pa[it][j]) * sscl[colb + j] + ssft[colb + j], 0.f);
          h[j] = (short)f2bf(f);
        }
      }
      *(s16x8*)(Al + ((r * 128 + c * 16) ^ ((r & 7) << 4))) = h;
      *(s16x8*)(Bl + ((r * 128 + c * 16) ^ ((r & 7) << 4))) = pb[it];
    }
  };
  auto compute = [&]() {
#pragma unroll
    for (int kc = 0; kc < 2; ++kc) {
      int co = kc * 64 + lg * 16;
      s16x8 a[4], b[4];
#pragma unroll
      for (int mt = 0; mt < 4; ++mt) {
        int r = wr * 64 + mt * 16 + lr;
        a[mt] = *(const s16x8*)(Al + ((r * 128 + co) ^ ((r & 7) << 4)));
      }
#pragma unroll
      for (int ct = 0; ct < 4; ++ct) {
        int r = wc * 64 + ct * 16 + lr;
        b[ct] = *(const s16x8*)(Bl + ((r * 128 + co) ^ ((r & 7) << 4)));
      }
#pragma unroll
      for (int mt = 0; mt < 4; ++mt)
#pragma unroll
        for (int ct = 0; ct < 4; ++ct) mfma16(acc[mt][ct], a[mt], b[ct]);
    }
  };

  issue(0);
  __syncthreads();
  for (int st = 0; st < 7; ++st) {
    writeT(st);
    __syncthreads();
    if (st < 6) issue(st + 1);
    compute();
    if (st < 6) rawbar();
  }
  __syncthreads();
  float* S = (float*)Al;
#pragma unroll
  for (int ct = 0; ct < 4; ++ct) {
    float s = 0.f, qq = 0.f;
#pragma unroll
    for (int mt = 0; mt < 4; ++mt)
#pragma unroll
      for (int j = 0; j < 4; ++j) { float v = acc[mt][ct][j]; s += v; qq += v * v; }
    s += __shfl_xor(s, 16); s += __shfl_xor(s, 32);
    qq += __shfl_xor(qq, 16); qq += __shfl_xor(qq, 32);
    if (lane < 16) {
      S[wv * 128 + ct * 16 + lane] = s;
      S[wv * 128 + 64 + ct * 16 + lane] = qq;
    }
  }
  __syncthreads();
  {
    float* base = st3 + (sgrp & 7) * 512;
    if (t < 64) atomicAdd(base + cb * 128 + t, S[t] + S[256 + t]);
    else if (t < 128) atomicAdd(base + INC + cb * 128 + (t - 64), S[64 + t - 64] + S[320 + t - 64]);
    else if (t < 192) atomicAdd(base + cb * 128 + 64 + (t - 128), S[128 + t - 128] + S[384 + t - 128]);
    else atomicAdd(base + INC + cb * 128 + 64 + (t - 192), S[192 + t - 192] + S[448 + t - 192]);
  }
#pragma unroll
  for (int mt = 0; mt < 4; ++mt)
#pragma unroll
    for (int ct = 0; ct < 4; ++ct)
#pragma unroll
      for (int j = 0; j < 4; ++j) {
        int r = rowbase + wr * 64 + mt * 16 + lg * 4 + j;
        int col = cb * 128 + wc * 64 + ct * 16 + lr;
        if (r < NPTS) ob[(size_t)r * INC + col] = f2bf(acc[mt][ct][j]);
      }
}

// ---------------- mix: SPX = [relu(bnc(Z)) +] relu(bn1(Y slab)), fused stats ----------------
template <int HASZ>
__global__ __launch_bounds__(256) void k_mix(const u16* __restrict__ ys, int slab,
    const float* __restrict__ ST, int yoff,
    const float* __restrict__ g1, const float* __restrict__ b1,
    const u16* __restrict__ z, const float* __restrict__ stc,
    const float* __restrict__ gcb, const float* __restrict__ bcb,
    u16* __restrict__ spx) {
  __shared__ float s1c[104], f1c[104], szc[104], fzc[104];
  const int t = threadIdx.x;
  if (t < 104) {
    float s = 0.f, q = 0.f;
#pragma unroll
    for (int bk = 0; bk < 8; ++bk) { s += ST[bk * 832 + yoff + t]; q += ST[bk * 832 + 416 + yoff + t]; }
    float m = s * (1.f / NPTS);
    float var = q * (1.f / NPTS) - m * m;
    float rs = rsqrtf(var + EPSV);
    float sc = rs * g1[yoff + t];
    s1c[t] = sc; f1c[t] = b1[yoff + t] - m * sc;
  } else if (HASZ && t >= 128 && t < 232) {
    int c = t - 128;
    float s = 0.f, q = 0.f;
#pragma unroll
    for (int bk = 0; bk < 8; ++bk) { s += stc[bk * 208 + c]; q += stc[bk * 208 + 104 + c]; }
    float m = s * (1.f / NPTS);
    float var = q * (1.f / NPTS) - m * m;
    float rs = rsqrtf(var + EPSV);
    float sc = rs * gcb[c];
    szc[c] = sc; fzc[c] = bcb[c] - m * sc;
  }
  __syncthreads();
  const u16* yb = ys + (size_t)slab * NPTS * WID;
  const int total = NPTS * 13;
  for (int i = blockIdx.x * 256 + t; i < total; i += gridDim.x * 256) {
    int r = i / 13, cc = i - r * 13;
    s16x8 y = *(const s16x8*)(yb + (size_t)r * WID + cc * 8);
    s16x8 zv;
    if (HASZ) zv = *(const s16x8*)(z + (size_t)r * WID + cc * 8);
    s16x8 o;
#pragma unroll
    for (int j = 0; j < 8; ++j) {
      int c = cc * 8 + j;
      float f = fmaxf(bf2f((u16)y[j]) * s1c[c] + f1c[c], 0.f);
      if (HASZ) f += fmaxf(bf2f((u16)zv[j]) * szc[c] + fzc[c], 0.f);
      o[j] = (short)f2bf(f);
    }
    *(s16x8*)(spx + (size_t)r * SPAD + cc * 8) = o;
  }
}

// ---------------- final: out = relu(bn3(ob) + xb), fused stats ----------------
__global__ __launch_bounds__(256) void k_final(const u16* __restrict__ ob,
    const u16* __restrict__ xb, const float* __restrict__ ST3,
    const float* __restrict__ g3, const float* __restrict__ b3,
    float* __restrict__ out) {
  __shared__ float sc3[256], sf3[256];
  const int t = threadIdx.x;
  {
    float s = 0.f, q = 0.f;
#pragma unroll
    for (int bk = 0; bk < 8; ++bk) { s += ST3[bk * 512 + t]; q += ST3[bk * 512 + 256 + t]; }
    float m = s * (1.f / NPTS);
    float var = q * (1.f / NPTS) - m * m;
    float rs = rsqrtf(var + EPSV);
    float sc = rs * g3[t];
    sc3[t] = sc; sf3[t] = b3[t] - m * sc;
  }
  __syncthreads();
  const int total = NPTS * 32;
  for (int i = blockIdx.x * 256 + t; i < total; i += gridDim.x * 256) {
    int r = i >> 5, cc = i & 31;
    s16x8 o = *(const s16x8*)(ob + (size_t)r * INC + cc * 8);
    s16x8 xv = *(const s16x8*)(xb + (size_t)r * INC + cc * 8);
    f32x4 v0, v1;
#pragma unroll
    for (int j = 0; j < 4; ++j) {
      int c = cc * 8 + j;
      v0[j] = fmaxf(bf2f((u16)o[j]) * sc3[c] + sf3[c] + bf2f((u16)xv[j]), 0.f);
    }
#pragma unroll
    for (int j = 0; j < 4; ++j) {
      int c = cc * 8 + 4 + j;
      v1[j] = fmaxf(bf2f((u16)o[4 + j]) * sc3[c] + sf3[c] + bf2f((u16)xv[4 + j]), 0.f);
    }
    f32x4* dp = (f32x4*)(out + (size_t)r * INC + cc * 8);
    dp[0] = v0; dp[1] = v1;
  }
}

// ---------------- launch ----------------
extern "C" void kernel_launch(void* const* d_in, const int* in_sizes, int n_in,
                              void* d_out, int out_size, void* d_ws, size_t ws_size,
                              hipStream_t stream) {
  const float* x  = (const float*)d_in[0];
  const int* nbr  = (const int*)d_in[1];
  const float* W1 = (const float*)d_in[2];
  const float* g1 = (const float*)d_in[3];
  const float* b1 = (const float*)d_in[4];
  const float* Wc = (const float*)d_in[5];
  const float* gc = (const float*)d_in[6];
  const float* bc = (const float*)d_in[7];
  const float* W3 = (const float*)d_in[8];
  const float* g3 = (const float*)d_in[9];
  const float* b3 = (const float*)d_in[10];
  float* out = (float*)d_out;

  char* ws = (char*)d_ws;
  size_t off = 0;
  auto alloc = [&](size_t nbytes) {
    char* p = ws + off;
    off += (nbytes + 255) & ~(size_t)255;
    return p;
  };
  u16* W1T = (u16*)alloc(416 * 256 * 2);
  u16* W3T = (u16*)alloc(256 * 416 * 2);
  u16* WCT = (u16*)alloc((size_t)3 * 27 * 112 * 104 * 2);
  u16* XB  = (u16*)alloc((size_t)NPTS * INC * 2);
  u16* Y1S = (u16*)alloc((size_t)4 * NPTS * WID * 2);
  u16* Z0  = (u16*)alloc((size_t)NPTS * WID * 2);
  u16* Z1  = (u16*)alloc((size_t)NPTS * WID * 2);
  u16* Z2  = (u16*)alloc((size_t)NPTS * WID * 2);
  u16* OB  = (u16*)alloc((size_t)NPTS * INC * 2);
  u16* SPX = (u16*)alloc((size_t)(NPTS + 1) * SPAD * 2);
  float* ST = (float*)alloc(ST_TOTAL * 4);
  float* ST1  = ST + ST1_OFF;
  float* STC0 = ST + STC_OFF;
  float* STC1 = ST + STC_OFF + STC_SZ;
  float* STC2 = ST + STC_OFF + 2 * STC_SZ;
  float* ST3  = ST + ST3_OFF;

  k_prep<<<3217, 256, 0, stream>>>(W1, W3, Wc, W1T, W3T, WCT, ST, SPX, x, XB);

  k_gemm1<<<3136, 256, 0, stream>>>(XB, W1T, Y1S, ST1);
  k_mix<0><<<2048, 256, 0, stream>>>(Y1S, 0, ST1, 0, g1, b1,
                                     nullptr, nullptr, nullptr, nullptr, SPX);

  const size_t WCL = (size_t)27 * 112 * WID;
  // branch 0
  k_conv<<<782, 256, 0, stream>>>(SPX, nbr, WCT, Z0, STC0);
  // branch 1
  k_mix<1><<<2048, 256, 0, stream>>>(Y1S, 1, ST1, 104, g1, b1,
                                     Z0, STC0, gc, bc, SPX);
  k_conv<<<782, 256, 0, stream>>>(SPX, nbr, WCT + WCL, Z1, STC1);
  // branch 2
  k_mix<1><<<2048, 256, 0, stream>>>(Y1S, 2, ST1, 208, g1, b1,
                                     Z1, STC1, gc + 104, bc + 104, SPX);
  k_conv<<<782, 256, 0, stream>>>(SPX, nbr, WCT + 2 * WCL, Z2, STC2);

  k_gemm3<<<1568, 256, 0, stream>>>(Z0, Z1, Z2, Y1S, W3T, ST, gc, bc, g1, b1, OB, ST3);
  k_final<<<2048, 256, 0, stream>>>(OB, XB, ST3, g3, b3, out);
}